// Round 2
// baseline (2783.000 us; speedup 1.0000x reference)
//
#include <hip/hip_runtime.h>

#define N 8192
#define GBLK 512   // fused grid: 512 blocks x 16 rows
#define RPB 16     // rows per fused block
#define TPB 512    // 8 waves per fused block

// ---- bf16 helpers (manual, branch-free RNE) ----
__device__ __forceinline__ unsigned int f2bf_rne(float f) {
    unsigned int u = __float_as_uint(f);
    u += 0x7fffu + ((u >> 16) & 1u);
    return u >> 16;
}
__device__ __forceinline__ unsigned int pack2(float a, float b) {
    return f2bf_rne(a) | (f2bf_rne(b) << 16);
}
__device__ __forceinline__ float bf_lo(unsigned int u) { return __uint_as_float(u << 16); }
__device__ __forceinline__ float bf_hi(unsigned int u) { return __uint_as_float(u & 0xffff0000u); }

// prep: A = bf16(|W|) row-major, R_i = 1/rowsum(A_i)  (iteration-1 row pass).
// 2048 blocks x 256; one row per wave.
__global__ __launch_bounds__(256) void prep(const float* __restrict__ W,
                                            unsigned int* __restrict__ A,
                                            float* __restrict__ R) {
    const int tid = threadIdx.x;
    const int wave = tid >> 6, lane = tid & 63;
    const int row = blockIdx.x * 4 + wave;
    const float4* wr = (const float4*)(W + (size_t)row * N);
    uint4* ar = (uint4*)(A + (size_t)row * (N / 2));
    float s = 0.0f;
#pragma unroll 4
    for (int it = 0; it < 16; it++) {
        int g = it * 64 + lane;
        float4 w0 = wr[2 * g];
        float4 w1 = wr[2 * g + 1];
        uint4 p;
        p.x = pack2(fabsf(w0.x), fabsf(w0.y));
        p.y = pack2(fabsf(w0.z), fabsf(w0.w));
        p.z = pack2(fabsf(w1.x), fabsf(w1.y));
        p.w = pack2(fabsf(w1.z), fabsf(w1.w));
        ar[g] = p;
        // sum the quantized values so later passes are self-consistent
        s += ((bf_lo(p.x) + bf_hi(p.x)) + (bf_lo(p.y) + bf_hi(p.y))) +
             ((bf_lo(p.z) + bf_hi(p.z)) + (bf_lo(p.w) + bf_hi(p.w)));
    }
    for (int off = 32; off > 0; off >>= 1) s += __shfl_down(s, off);
    if (lane == 0) R[row] = 1.0f / s;
}

// fused_pass: single sweep of A per iteration.
//  phase A (unless SKIP_ROWS): R_i = 1/(sum_j A_ij * crcp_j) for this block's 16 rows
//  phase B: partial[block][j] = sum over the 16 register-resident rows of A_ij * R_i
// 512 blocks x 512 thr (8 waves, 2 rows/wave held in 128 VGPRs).
// LDS: crcp (float4-swizzled, conflict-free b128 reads) + csum (float-swizzled,
// 2-way ds_add_f32) = exactly 64 KB.
template <int SKIP_ROWS>
__global__ __launch_bounds__(TPB, 2) void fused_pass(
    const unsigned short* __restrict__ Au,
    const float* __restrict__ crcp_g,   // 1/colsum from previous iteration
    const float* __restrict__ R_in,     // used only when SKIP_ROWS
    float* __restrict__ R_out,
    float* __restrict__ partial)        // [GBLK][N]
{
    __shared__ float crcp[N];  // 32 KB, float4 slot f stored at f ^ ((f>>3)&1)
    __shared__ float csum[N];  // 32 KB, col c stored at c ^ ((c>>6)&7)

    const int tid = threadIdx.x;
    const int wave = tid >> 6, lane = tid & 63;

    // zero csum (zero is swizzle-invariant) + stage swizzled crcp
    {
        float4* dz = (float4*)csum;
        const float4 z = {0.f, 0.f, 0.f, 0.f};
#pragma unroll
        for (int k = 0; k < 4; k++) dz[k * TPB + tid] = z;
    }
    if (!SKIP_ROWS) {
        const float4* src = (const float4*)crcp_g;
        float4* dc = (float4*)crcp;
#pragma unroll
        for (int k = 0; k < 4; k++) {
            int f = k * TPB + tid;
            dc[f ^ ((f >> 3) & 1)] = src[f];
        }
    }
    __syncthreads();

    // load this wave's two rows fully into registers (32 x dwordx4 in flight)
    const int rowA = blockIdx.x * RPB + wave * 2;
    const uint4* pA = (const uint4*)(Au + (size_t)rowA * N);
    const uint4* pB = (const uint4*)(Au + (size_t)(rowA + 1) * N);
    uint4 ra[16], rb[16];
#pragma unroll
    for (int g = 0; g < 16; g++) ra[g] = pA[g * 64 + lane];
#pragma unroll
    for (int g = 0; g < 16; g++) rb[g] = pB[g * 64 + lane];

    float Rva, Rvb;
    if (SKIP_ROWS) {
        Rva = R_in[rowA];
        Rvb = R_in[rowA + 1];
    } else {
        // phase A: dot both rows with crcp (swizzled, conflict-free b128 reads)
        const float4* c4 = (const float4*)crcp;
        const int sw = (lane >> 2) & 1;
        float4 aA = {0.f, 0.f, 0.f, 0.f}, aB = {0.f, 0.f, 0.f, 0.f};
#pragma unroll
        for (int g = 0; g < 16; g++) {
            const int s0 = g * 128 + 2 * lane;   // logical float4 slot (cols s0*4..)
            float4 c0 = c4[s0 + sw];             // logical slot s0
            float4 c1 = c4[s0 + 1 - sw];         // logical slot s0+1
            aA.x = fmaf(bf_lo(ra[g].x), c0.x, aA.x);
            aA.y = fmaf(bf_hi(ra[g].x), c0.y, aA.y);
            aA.z = fmaf(bf_lo(ra[g].y), c0.z, aA.z);
            aA.w = fmaf(bf_hi(ra[g].y), c0.w, aA.w);
            aA.x = fmaf(bf_lo(ra[g].z), c1.x, aA.x);
            aA.y = fmaf(bf_hi(ra[g].z), c1.y, aA.y);
            aA.z = fmaf(bf_lo(ra[g].w), c1.z, aA.z);
            aA.w = fmaf(bf_hi(ra[g].w), c1.w, aA.w);
            aB.x = fmaf(bf_lo(rb[g].x), c0.x, aB.x);
            aB.y = fmaf(bf_hi(rb[g].x), c0.y, aB.y);
            aB.z = fmaf(bf_lo(rb[g].y), c0.z, aB.z);
            aB.w = fmaf(bf_hi(rb[g].y), c0.w, aB.w);
            aB.x = fmaf(bf_lo(rb[g].z), c1.x, aB.x);
            aB.y = fmaf(bf_hi(rb[g].z), c1.y, aB.y);
            aB.z = fmaf(bf_lo(rb[g].w), c1.z, aB.z);
            aB.w = fmaf(bf_hi(rb[g].w), c1.w, aB.w);
        }
        float sA = (aA.x + aA.y) + (aA.z + aA.w);
        float sB = (aB.x + aB.y) + (aB.z + aB.w);
#pragma unroll
        for (int off = 32; off > 0; off >>= 1) {
            sA += __shfl_xor(sA, off);
            sB += __shfl_xor(sB, off);
        }
        Rva = 1.0f / sA;
        Rvb = 1.0f / sB;
        if (lane == 0) {
            R_out[rowA] = Rva;
            R_out[rowA + 1] = Rvb;
        }
    }

    // phase B: scatter-add the register rows into swizzled csum (2-way banks).
    // cb has low-3 bits zero, so cb + (d ^ xl) == (cb + d) ^ xl : in-group, safe.
    const int xl = (lane >> 3) & 7;
#pragma unroll
    for (int g = 0; g < 16; g++) {
        const int cb = g * 512 + lane * 8;
        float v0 = fmaf(bf_lo(ra[g].x), Rva, bf_lo(rb[g].x) * Rvb);
        float v1 = fmaf(bf_hi(ra[g].x), Rva, bf_hi(rb[g].x) * Rvb);
        float v2 = fmaf(bf_lo(ra[g].y), Rva, bf_lo(rb[g].y) * Rvb);
        float v3 = fmaf(bf_hi(ra[g].y), Rva, bf_hi(rb[g].y) * Rvb);
        float v4 = fmaf(bf_lo(ra[g].z), Rva, bf_lo(rb[g].z) * Rvb);
        float v5 = fmaf(bf_hi(ra[g].z), Rva, bf_hi(rb[g].z) * Rvb);
        float v6 = fmaf(bf_lo(ra[g].w), Rva, bf_lo(rb[g].w) * Rvb);
        float v7 = fmaf(bf_hi(ra[g].w), Rva, bf_hi(rb[g].w) * Rvb);
        atomicAdd(&csum[cb + (0 ^ xl)], v0);
        atomicAdd(&csum[cb + (1 ^ xl)], v1);
        atomicAdd(&csum[cb + (2 ^ xl)], v2);
        atomicAdd(&csum[cb + (3 ^ xl)], v3);
        atomicAdd(&csum[cb + (4 ^ xl)], v4);
        atomicAdd(&csum[cb + (5 ^ xl)], v5);
        atomicAdd(&csum[cb + (6 ^ xl)], v6);
        atomicAdd(&csum[cb + (7 ^ xl)], v7);
    }
    __syncthreads();

    // export csum (un-swizzled) -> partial[block], coalesced float4 stores.
    // BUGFIX vs prev round: physical index is (c0+d) ^ x, NOT c0 + (d^x).
    // c0 = 4*f has bit 2 = f&1, so the old form walked out of the 8-group
    // (up to csum[8195] -> OOB LDS read -> NaN colsums). (c0+d)^x only flips
    // low-3 bits within the aligned group: always in [0,8191], bijective.
    float4* dst = (float4*)(partial + (size_t)blockIdx.x * N);
#pragma unroll
    for (int k = 0; k < 4; k++) {
        const int f = k * TPB + tid;
        const int c0 = 4 * f;
        const int x = (c0 >> 6) & 7;
        float4 v;
        v.x = csum[(c0 + 0) ^ x];
        v.y = csum[(c0 + 1) ^ x];
        v.z = csum[(c0 + 2) ^ x];
        v.w = csum[(c0 + 3) ^ x];
        dst[f] = v;
    }
}

// reduce_cols: crcp_g[j] = 1 / sum over 512 partial slices.  256 blocks x 256:
// block = 32 cols, 8 slice-groups of 64; coalesced 128-B rows, ~16 MB total.
__global__ __launch_bounds__(256) void reduce_cols(const float* __restrict__ partial,
                                                   float* __restrict__ crcp_g) {
    __shared__ float sh[256];
    const int tid = threadIdx.x;
    const int col = blockIdx.x * 32 + (tid & 31);
    const int grp = tid >> 5;
    const float* p = partial + (size_t)(grp * 64) * N + col;
    float s = 0.f;
#pragma unroll 8
    for (int k = 0; k < 64; k++) s += p[(size_t)k * N];
    sh[tid] = s;
    __syncthreads();
    if (tid < 32) {
        float t = sh[tid];
#pragma unroll
        for (int g = 1; g < 8; g++) t += sh[g * 32 + tid];
        crcp_g[col] = 1.0f / t;
    }
}

// finalize: out_ij = R_i * |W_ij| * crcp_j.  Exact fp32 W.
__global__ __launch_bounds__(256) void finalize(const float* __restrict__ W,
                                                const float* __restrict__ R,
                                                const float* __restrict__ crcp_g,
                                                float* __restrict__ out) {
    __shared__ float crl[N];
    const int tid = threadIdx.x;
#pragma unroll
    for (int k = 0; k < 8; k++) {
        int f = k * 256 + tid;
        ((float4*)crl)[f] = ((const float4*)crcp_g)[f];
    }
    __syncthreads();

    const int wave = tid >> 6, lane = tid & 63;
    const int row0 = blockIdx.x * 8 + wave * 2;
    for (int rr = 0; rr < 2; rr++) {
        const int row = row0 + rr;
        const float r = R[row];
        const float4* wr = (const float4*)(W + (size_t)row * N);
        float4* orow = (float4*)(out + (size_t)row * N);
#pragma unroll 4
        for (int k = 0; k < 32; k++) {
            int f = k * 64 + lane;
            float4 w = wr[f];
            float4 c = ((const float4*)crl)[f];
            float4 o;
            o.x = r * fabsf(w.x) * c.x;
            o.y = r * fabsf(w.y) * c.y;
            o.z = r * fabsf(w.z) * c.z;
            o.w = r * fabsf(w.w) * c.w;
            orow[f] = o;
        }
    }
}

extern "C" void kernel_launch(void* const* d_in, const int* in_sizes, int n_in,
                              void* d_out, int out_size, void* d_ws, size_t ws_size,
                              hipStream_t stream) {
    const float* W = (const float*)d_in[0];
    float* out = (float*)d_out;

    // bf16 |W| scratch lives in the FIRST HALF of d_out (134 MB of 268 MB).
    unsigned short* A = (unsigned short*)d_out;

    // vectors in d_ws: R | crcp (64 KB).  partial (16 MB) in ws if it fits,
    // else in the free tail of d_out (dead by the time finalize overwrites it).
    float* R = (float*)d_ws;
    float* crcp_g = R + N;
    float* partial;
    const size_t vec_bytes = (size_t)2 * N * sizeof(float);
    const size_t part_bytes = (size_t)GBLK * N * sizeof(float);
    if (ws_size >= vec_bytes + part_bytes)
        partial = crcp_g + N;
    else
        partial = (float*)((char*)d_out + (size_t)N * N * 2);

    // iter 1: prep = bf16 convert + row pass; fused<1> = col sweep using prep's R
    prep<<<2048, 256, 0, stream>>>(W, (unsigned int*)A, R);
    fused_pass<1><<<GBLK, TPB, 0, stream>>>(A, crcp_g, R, R, partial);
    reduce_cols<<<256, 256, 0, stream>>>(partial, crcp_g);

    // iters 2..10: ONE sweep of A each (rows + cols fused), then 3-us reduce
    for (int k = 2; k <= 10; k++) {
        fused_pass<0><<<GBLK, TPB, 0, stream>>>(A, crcp_g, R, R, partial);
        reduce_cols<<<256, 256, 0, stream>>>(partial, crcp_g);
    }
    finalize<<<1024, 256, 0, stream>>>(W, R, crcp_g, out);
}